// Round 9
// baseline (4453.457 us; speedup 1.0000x reference)
//
#include <hip/hip_runtime.h>

#define NROWS 16384
#define DIN   1024
#define DH    4096
#define DZ    256
#define KCB   4096
#define KSPLIT 8

typedef _Float16 f16x8 __attribute__((ext_vector_type(8)));
typedef _Float16 f16x4 __attribute__((ext_vector_type(4)));
typedef float    f32x4 __attribute__((ext_vector_type(4)));

#define INV4096 2.44140625e-4f
#define F16_MIN_NORMAL 6.103515625e-05f

struct Split { _Float16 h, l; };

// Split v into h + l/4096 with h, l normal-or-zero f16 (denormal-safe).
__device__ inline Split splitf(float v) {
    _Float16 hh = (_Float16)v;
    float hf = (float)hh;
    if (fabsf(hf) < F16_MIN_NORMAL) { hh = (_Float16)0.0f; hf = 0.0f; }
    Split s;
    s.h = hh;
    s.l = (_Float16)((v - hf) * 4096.0f);
    return s;
}

__device__ inline void gload_lds16(const void* g, void* l) {
    __builtin_amdgcn_global_load_lds(
        (const __attribute__((address_space(1))) void*)g,
        (__attribute__((address_space(3))) void*)l, 16, 0, 0);
}

// ---------------------------------------------------------------------------
__global__ void k_init_best(unsigned long long* best) {
    int i = blockIdx.x * 256 + threadIdx.x;
    if (i < NROWS) best[i] = 0xFFFFFFFFFFFFFFFFULL;
}

// Element-wise fp32 -> split f16 pair (residual form). n multiple of 1024.
__global__ void k_esplit(const float* __restrict__ X, _Float16* __restrict__ H,
                         _Float16* __restrict__ L, size_t n) {
    size_t i = ((size_t)blockIdx.x * 256 + threadIdx.x) * 4;
    if (i >= n) return;
    float4 v = *(const float4*)(X + i);
    f16x4 hv, lv;
    Split s0 = splitf(v.x), s1 = splitf(v.y), s2 = splitf(v.z), s3 = splitf(v.w);
    hv[0] = s0.h; hv[1] = s1.h; hv[2] = s2.h; hv[3] = s3.h;
    lv[0] = s0.l; lv[1] = s1.l; lv[2] = s2.l; lv[3] = s3.l;
    *(f16x4*)(H + i) = hv;
    *(f16x4*)(L + i) = lv;
}

// Transpose + split: B[K][N] fp32 -> Th/Tl [N][K] f16. K,N multiples of 32.
__global__ void k_tsplit(const float* __restrict__ B, _Float16* __restrict__ Th,
                         _Float16* __restrict__ Tl, int K, int N) {
    __shared__ float tile[32][33];
    const int k0 = blockIdx.x * 32, n0 = blockIdx.y * 32;
    const int tx = threadIdx.x, ty = threadIdx.y;   // block (32,8)
#pragma unroll
    for (int i = 0; i < 4; i++)
        tile[ty + i * 8][tx] = B[(size_t)(k0 + ty + i * 8) * N + n0 + tx];
    __syncthreads();
#pragma unroll
    for (int i = 0; i < 4; i++) {
        float v = tile[tx][ty + i * 8];
        Split s = splitf(v);
        size_t o = (size_t)(n0 + ty + i * 8) * K + k0 + tx;
        Th[o] = s.h; Tl[o] = s.l;
    }
}

// ---------------------------------------------------------------------------
// Split-precision f16 MFMA GEMM (3-stream).  128x128 tile, BK=32, 4 waves
// (2Mx2N), per-wave 64x64.  A-stream is DIRECT global->register, prefetched
// ONE K-TILE AHEAD into a ping-pong register set (loads issue at the top of
// tile t, are forced complete by the boundary vmcnt(0), and are consumed in
// tile t+1 -- a full-tile ~1000-cycle latency window).  LDS carries only B
// (double-buffered 2 x 8 KB), halving the LDS pipe so it no longer rivals
// the MFMA pipe; the barrier-lockstep serialization measured in r2/r3/r6
// then costs far less.
// Hardened vs r7: no s_setprio; B-frags consumed in two fj-pairs to cap
// live registers (~215 VGPR peak, no spill under launch_bounds(256,2)).
// B LDS XOR-swizzled (phys kslot = q ^ ((row>>1)&3)); global_load_lds
// writes linearly so the inverse permutation pre-swizzles the global
// source address.  A frags need no swizzle (registers).
// Main loop unrolled by 2 (all ntseg values are even) for the A ping-pong.
// MODE 0: Ch/Cl = split(relu(C+bias))
// MODE 1: Ch/Cl = split(C+bias)
// MODE 2: split-K partial: Cf[(bz*M + row)*N + col] = C  (grid.z = KSPLIT)
// MODE 3: distance epilogue d = Z2[m] + C2[n] - 2*C; packed atomicMin(best)
template <int MODE>
__global__ __launch_bounds__(256, 2)
void k_gemm8(const _Float16* __restrict__ Ah, const _Float16* __restrict__ Al,
             const _Float16* __restrict__ Bh, const _Float16* __restrict__ Bl,
             const float* __restrict__ bias,
             _Float16* __restrict__ Ch, _Float16* __restrict__ Cl,
             float* __restrict__ Cf,
             const float* __restrict__ Z2, const float* __restrict__ C2,
             unsigned long long* __restrict__ best,
             int M, int N, int K, int ntseg) {
    constexpr int BUF = 8192;                  // f16 per buffer = 16 KB
    // per buffer: Bh @0 (128x32 f16), Bl @4096
    __shared__ __align__(16) _Float16 lds[2 * BUF];   // 32 KB

    const int tid  = threadIdx.x;
    const int w    = tid >> 6;
    const int l    = tid & 63;
    const int wm   = w >> 1, wn = w & 1;       // 2Mx2N wave grid
    const int quad = l >> 4, lcol = l & 15;
    const long m0 = (long)blockIdx.y * 128;
    const long n0 = (long)blockIdx.x * 128;
    const int kbase = (int)blockIdx.z * ntseg * 32;   // split-K (MODE 2)

    // Swizzled per-lane B read offset (f16 units) within a matrix segment.
    const int lidx = lcol * 32 + ((quad ^ ((l >> 1) & 3)) * 8);

    // A direct-to-reg pointers: lane covers A[m0+wm*64+fi*16+lcol]
    // [k + quad*8 .. +8] (16 B) -- exactly the MFMA A-frag (r4-verified).
    const _Float16* pAh = Ah + (size_t)(m0 + wm * 64 + lcol) * K + quad * 8 + kbase;
    const _Float16* pAl = Al + (size_t)(m0 + wm * 64 + lcol) * K + quad * 8 + kbase;

    // B staging: waves 0,1 stage Bh rows [0,64)/[64,128); waves 2,3 same for
    // Bl.  4 x gload_lds16 per wave (16 rows each).  Lane: row16 = l>>2,
    // phys k-slot = l&3, logical k-slot = (l&3)^((l>>3)&3) (inverse swizzle).
    const _Float16* gB = (w < 2) ? Bh : Bl;
    const int grow = l >> 2;
    const int kq8  = (((l & 3) ^ ((l >> 3) & 3)) << 3);
    const _Float16* gBbase =
        gB + (size_t)(n0 + (w & 1) * 64 + grow) * K + kq8 + kbase;
    const int wseg = (w >> 1) * 4096 + (w & 1) * 2048;  // LDS dst (f16)

    f32x4 acc_h[4][4], acc_x[4][4];
#pragma unroll
    for (int i = 0; i < 4; i++)
#pragma unroll
        for (int j = 0; j < 4; j++) {
            acc_h[i][j] = (f32x4){0.f, 0.f, 0.f, 0.f};
            acc_x[i][j] = (f32x4){0.f, 0.f, 0.f, 0.f};
        }

#define STAGEB(bi, koff) do { \
        _Float16* d = lds + (bi) * BUF + wseg; \
        const _Float16* g = gBbase + (koff); \
        gload_lds16(g,                   d);        \
        gload_lds16(g + (size_t)16 * K,  d + 512);  \
        gload_lds16(g + (size_t)32 * K,  d + 1024); \
        gload_lds16(g + (size_t)48 * K,  d + 1536); } while (0)

#define LDAG(ah, al, koff) do { \
        ah[0] = *(const f16x8*)(pAh + (size_t)(koff)); \
        ah[1] = *(const f16x8*)(pAh + (size_t)16 * K + (koff)); \
        ah[2] = *(const f16x8*)(pAh + (size_t)32 * K + (koff)); \
        ah[3] = *(const f16x8*)(pAh + (size_t)48 * K + (koff)); \
        al[0] = *(const f16x8*)(pAl + (size_t)(koff)); \
        al[1] = *(const f16x8*)(pAl + (size_t)16 * K + (koff)); \
        al[2] = *(const f16x8*)(pAl + (size_t)32 * K + (koff)); \
        al[3] = *(const f16x8*)(pAl + (size_t)48 * K + (koff)); } while (0)

// acc[fi][fjg] += 3-stream product of A-frag (ah,al)[fi] and B-frag fb[fjl].
#define MM3(ah, al, fi, fjg, fjl) do { \
        acc_h[fi][fjg] = __builtin_amdgcn_mfma_f32_16x16x32_f16(ah[fi], fb_h[fjl], acc_h[fi][fjg], 0, 0, 0); \
        acc_x[fi][fjg] = __builtin_amdgcn_mfma_f32_16x16x32_f16(ah[fi], fb_l[fjl], acc_x[fi][fjg], 0, 0, 0); \
        acc_x[fi][fjg] = __builtin_amdgcn_mfma_f32_16x16x32_f16(al[fi], fb_h[fjl], acc_x[fi][fjg], 0, 0, 0); } while (0)

// Consume one K-tile from LDS buffer bi with A-frag set (ah, al).
// B-frags processed in two fj-pairs to cap live registers.
#define BODY(ah, al, bi) do { \
        const _Float16* sBh_ = lds + (bi) * BUF; \
        const _Float16* sBl_ = sBh_ + 4096; \
        f16x8 fb_h[2], fb_l[2]; \
        fb_h[0] = *(const f16x8*)(sBh_ + (wn * 64 +  0) * 32 + lidx); \
        fb_l[0] = *(const f16x8*)(sBl_ + (wn * 64 +  0) * 32 + lidx); \
        fb_h[1] = *(const f16x8*)(sBh_ + (wn * 64 + 16) * 32 + lidx); \
        fb_l[1] = *(const f16x8*)(sBl_ + (wn * 64 + 16) * 32 + lidx); \
        MM3(ah, al, 0, 0, 0); MM3(ah, al, 1, 0, 0); \
        MM3(ah, al, 2, 0, 0); MM3(ah, al, 3, 0, 0); \
        MM3(ah, al, 0, 1, 1); MM3(ah, al, 1, 1, 1); \
        MM3(ah, al, 2, 1, 1); MM3(ah, al, 3, 1, 1); \
        fb_h[0] = *(const f16x8*)(sBh_ + (wn * 64 + 32) * 32 + lidx); \
        fb_l[0] = *(const f16x8*)(sBl_ + (wn * 64 + 32) * 32 + lidx); \
        fb_h[1] = *(const f16x8*)(sBh_ + (wn * 64 + 48) * 32 + lidx); \
        fb_l[1] = *(const f16x8*)(sBl_ + (wn * 64 + 48) * 32 + lidx); \
        MM3(ah, al, 0, 2, 0); MM3(ah, al, 1, 2, 0); \
        MM3(ah, al, 2, 2, 0); MM3(ah, al, 3, 2, 0); \
        MM3(ah, al, 0, 3, 1); MM3(ah, al, 1, 3, 1); \
        MM3(ah, al, 2, 3, 1); MM3(ah, al, 3, 3, 1); } while (0)

    f16x8 fa0_h[4], fa0_l[4], fa1_h[4], fa1_l[4];

    // ---- prologue: A frags tile 0 -> set 0; B tile 0 -> buf 0 ----
    LDAG(fa0_h, fa0_l, 0);
    STAGEB(0, 0);
    asm volatile("s_waitcnt vmcnt(0)" ::: "memory");
    __builtin_amdgcn_s_barrier();

    // ntseg is even for every use (32 / 128 / 16 / 8).
    for (int t = 0; t < ntseg; t += 2) {
        const int koff1 = (t + 1) * 32;
        const int koff2 = (t + 2) * 32;
        const bool st2 = (t + 2) < ntseg;

        // ---- even tile t: prefetch t+1 (A->set1, B->buf1), consume set0/buf0
        LDAG(fa1_h, fa1_l, koff1);
        STAGEB(1, koff1);
        BODY(fa0_h, fa0_l, 0);
        asm volatile("s_waitcnt vmcnt(0)" ::: "memory");
        __builtin_amdgcn_s_barrier();

        // ---- odd tile t+1: prefetch t+2 (A->set0, B->buf0), consume set1/buf1
        if (st2) { LDAG(fa0_h, fa0_l, koff2); STAGEB(0, koff2); }
        BODY(fa1_h, fa1_l, 1);
        if (st2) asm volatile("s_waitcnt vmcnt(0)" ::: "memory");
        __builtin_amdgcn_s_barrier();
    }
#undef STAGEB
#undef LDAG
#undef MM3
#undef BODY

    if (MODE == 0 || MODE == 1) {
#pragma unroll
        for (int fj = 0; fj < 4; fj++) {
            const long col = n0 + wn * 64 + fj * 16 + lcol;
            const float bv = bias[col];
#pragma unroll
            for (int fi = 0; fi < 4; fi++) {
#pragma unroll
                for (int r = 0; r < 4; r++) {
                    const long row = m0 + wm * 64 + fi * 16 + quad * 4 + r;
                    float v = (acc_h[fi][fj][r] + INV4096 * acc_x[fi][fj][r]) + bv;
                    if (MODE == 0) v = fmaxf(v, 0.0f);
                    Split s = splitf(v);
                    const size_t o = (size_t)row * N + col;
                    Ch[o] = s.h; Cl[o] = s.l;
                }
            }
        }
    } else if (MODE == 2) {
        // split-K partial (fp32, no bias); unique (bz,row,col) per thread.
        const size_t pbase = (size_t)blockIdx.z * M * N;
#pragma unroll
        for (int fj = 0; fj < 4; fj++) {
            const long col = n0 + wn * 64 + fj * 16 + lcol;
#pragma unroll
            for (int fi = 0; fi < 4; fi++) {
#pragma unroll
                for (int r = 0; r < 4; r++) {
                    const long row = m0 + wm * 64 + fi * 16 + quad * 4 + r;
                    float v = acc_h[fi][fj][r] + INV4096 * acc_x[fi][fj][r];
                    Cf[pbase + (size_t)row * N + col] = v;
                }
            }
        }
    } else {
        float cc2[4];
#pragma unroll
        for (int fj = 0; fj < 4; fj++)
            cc2[fj] = C2[n0 + wn * 64 + fj * 16 + lcol];
#pragma unroll
        for (int fi = 0; fi < 4; fi++) {
#pragma unroll
            for (int r = 0; r < 4; r++) {
                const long row = m0 + wm * 64 + fi * 16 + quad * 4 + r;
                const float zz = Z2[row];
                float dmin = 3.4e38f; int didx = 0x7FFFFFFF;
#pragma unroll
                for (int fj = 0; fj < 4; fj++) {
                    float accv = acc_h[fi][fj][r] + INV4096 * acc_x[fi][fj][r];
                    int col = (int)(n0 + wn * 64 + fj * 16 + lcol);
                    float d = (zz + cc2[fj]) - 2.0f * accv;
                    if (d < dmin || (d == dmin && col < didx)) { dmin = d; didx = col; }
                }
#pragma unroll
                for (int off = 1; off < 16; off <<= 1) {
                    float ov = __shfl_xor(dmin, off, 64);
                    int   oi = __shfl_xor(didx, off, 64);
                    if (ov < dmin || (ov == dmin && oi < didx)) { dmin = ov; didx = oi; }
                }
                if (lcol == 0) {
                    unsigned long long pk =
                        ((unsigned long long)__float_as_uint(dmin) << 32) |
                        (unsigned long long)(unsigned)didx;
                    atomicMin(best + row, pk);
                }
            }
        }
    }
}

// ---------------------------------------------------------------------------
// Finalize z: sum KSPLIT split-K partials + bias, emit residual split
// (zH, zL) and row sq-norm z2.  One block per row, 64 threads (DZ=256).
__global__ void k_zfin(const float* __restrict__ zP, const float* __restrict__ b3,
                       _Float16* __restrict__ zH, _Float16* __restrict__ zL,
                       float* __restrict__ z2, int M) {
    const int row = blockIdx.x;
    const int t = threadIdx.x;                 // 64 lanes, 4 cols each
    float4 s = {0.f, 0.f, 0.f, 0.f};
#pragma unroll
    for (int ks = 0; ks < KSPLIT; ks++) {
        float4 v = *(const float4*)(zP + ((size_t)ks * M + row) * DZ + t * 4);
        s.x += v.x; s.y += v.y; s.z += v.z; s.w += v.w;
    }
    float4 bv = *(const float4*)(b3 + t * 4);
    s.x += bv.x; s.y += bv.y; s.z += bv.z; s.w += bv.w;
    Split p0 = splitf(s.x), p1 = splitf(s.y), p2 = splitf(s.z), p3 = splitf(s.w);
    f16x4 hv, lv;
    hv[0] = p0.h; hv[1] = p1.h; hv[2] = p2.h; hv[3] = p3.h;
    lv[0] = p0.l; lv[1] = p1.l; lv[2] = p2.l; lv[3] = p3.l;
    *(f16x4*)(zH + (size_t)row * DZ + t * 4) = hv;
    *(f16x4*)(zL + (size_t)row * DZ + t * 4) = lv;
    float ssq = s.x * s.x + s.y * s.y + s.z * s.z + s.w * s.w;
#pragma unroll
    for (int off = 32; off > 0; off >>= 1) ssq += __shfl_down(ssq, off, 64);
    if (t == 0) z2[row] = ssq;
}

// ---------------------------------------------------------------------------
__global__ void k_row_sq_norms(const float* __restrict__ X, float* __restrict__ out,
                               int ncols, int nrows) {
    const int wave = threadIdx.x >> 6;
    const int lane = threadIdx.x & 63;
    const long row = (long)blockIdx.x * 4 + wave;
    if (row >= nrows) return;
    const float* p = X + row * (long)ncols;
    float s = 0.0f;
    for (int c = lane * 4; c < ncols; c += 256) {
        float4 v = *(const float4*)(p + c);
        s += v.x * v.x + v.y * v.y + v.z * v.z + v.w * v.w;
    }
#pragma unroll
    for (int off = 32; off > 0; off >>= 1) s += __shfl_down(s, off, 64);
    if (lane == 0) out[row] = s;
}

__global__ void k_loss(const unsigned long long* __restrict__ best,
                       float* __restrict__ out) {
    __shared__ float red[256];
    float s = 0.0f;
    for (int i = threadIdx.x; i < NROWS; i += 256)
        s += __uint_as_float((unsigned)(best[i] >> 32));
    red[threadIdx.x] = s;
    __syncthreads();
    for (int st = 128; st > 0; st >>= 1) {
        if (threadIdx.x < st) red[threadIdx.x] += red[threadIdx.x + st];
        __syncthreads();
    }
    if (threadIdx.x == 0) out[(size_t)NROWS * DZ] = 2.0f * red[0];
}

__global__ void k_output(const float* __restrict__ CB,
                         const unsigned long long* __restrict__ best,
                         float* __restrict__ out) {
    const long n = blockIdx.x;
    const int t = threadIdx.x;      // 64 threads
    const int wd = (int)(unsigned)(best[n] & 0xFFFFFFFFULL);
    float4 v = *(const float4*)(CB + (size_t)wd * DZ + t * 4);
    *(float4*)(out + n * (size_t)DZ + t * 4) = v;
}

// ---------------------------------------------------------------------------
extern "C" void kernel_launch(void* const* d_in, const int* in_sizes, int n_in,
                              void* d_out, int out_size, void* d_ws, size_t ws_size,
                              hipStream_t stream) {
    const float* x  = (const float*)d_in[0];
    const float* W1 = (const float*)d_in[1];
    const float* b1 = (const float*)d_in[2];
    const float* W2 = (const float*)d_in[3];
    const float* b2 = (const float*)d_in[4];
    const float* W3 = (const float*)d_in[5];
    const float* b3 = (const float*)d_in[6];
    const float* cb = (const float*)d_in[7];
    float* out = (float*)d_out;

    // ---- workspace carve-up (bytes, 256-aligned) ----
    char* base = (char*)d_ws;
    size_t off = 0;
    auto alloc = [&](size_t bytes) -> void* {
        void* p = base + off;
        off = (off + bytes + 255) & ~(size_t)255;
        return p;
    };
    // fixed region: weights, codebook, z, norms, best
    _Float16* W1tH = (_Float16*)alloc((size_t)DH * DIN * 2);
    _Float16* W1tL = (_Float16*)alloc((size_t)DH * DIN * 2);
    _Float16* W2tH = (_Float16*)alloc((size_t)DH * DH * 2);
    _Float16* W2tL = (_Float16*)alloc((size_t)DH * DH * 2);
    _Float16* W3tH = (_Float16*)alloc((size_t)DZ * DH * 2);
    _Float16* W3tL = (_Float16*)alloc((size_t)DZ * DH * 2);
    _Float16* cbH  = (_Float16*)alloc((size_t)KCB * DZ * 2);
    _Float16* cbL  = (_Float16*)alloc((size_t)KCB * DZ * 2);
    _Float16* zH   = (_Float16*)alloc((size_t)NROWS * DZ * 2);
    _Float16* zL   = (_Float16*)alloc((size_t)NROWS * DZ * 2);
    float*    z2   = (float*)alloc((size_t)NROWS * 4);
    float*    c2   = (float*)alloc((size_t)KCB * 4);
    unsigned long long* best = (unsigned long long*)alloc((size_t)NROWS * 8);

    // chunk buffers: x split (4 KB/row) + h1/h2 splits (16 KB/row each)
    // + split-K z partials (KSPLIT * DZ * 4 = 8 KB/row)
    size_t rem = (ws_size > off) ? (ws_size - off) : 0;
    size_t perrow = (size_t)DIN * 2 * 2 + (size_t)DH * 2 * 4 + (size_t)KSPLIT * DZ * 4;
    size_t rc = rem / perrow;
    rc = (rc / 256) * 256;
    if (rc > NROWS) rc = NROWS;
    if (rc < 256)   rc = 256;
    _Float16* xcH = (_Float16*)alloc((size_t)rc * DIN * 2);
    _Float16* xcL = (_Float16*)alloc((size_t)rc * DIN * 2);
    _Float16* h1H = (_Float16*)alloc((size_t)rc * DH * 2);
    _Float16* h1L = (_Float16*)alloc((size_t)rc * DH * 2);
    _Float16* h2H = (_Float16*)alloc((size_t)rc * DH * 2);
    _Float16* h2L = (_Float16*)alloc((size_t)rc * DH * 2);
    float*    zP  = (float*)alloc((size_t)KSPLIT * rc * DZ * 4);

    // ---- one-time conversions ----
    k_init_best<<<(NROWS + 255) / 256, 256, 0, stream>>>(best);
    k_esplit<<<(unsigned)((size_t)KCB * DZ / 1024), 256, 0, stream>>>(
        cb, cbH, cbL, (size_t)KCB * DZ);
    k_tsplit<<<dim3(DIN / 32, DH / 32), dim3(32, 8), 0, stream>>>(W1, W1tH, W1tL, DIN, DH);
    k_tsplit<<<dim3(DH / 32, DH / 32),  dim3(32, 8), 0, stream>>>(W2, W2tH, W2tL, DH, DH);
    k_tsplit<<<dim3(DH / 32, DZ / 32),  dim3(32, 8), 0, stream>>>(W3, W3tH, W3tL, DH, DZ);

    // ---- MLP (chunked over rows; rows always a multiple of 256) ----
    for (size_t r0 = 0; r0 < NROWS; r0 += rc) {
        size_t rows = NROWS - r0;
        if (rows > rc) rows = rc;
        // x chunk -> split f16
        k_esplit<<<(unsigned)(rows * DIN / 1024), 256, 0, stream>>>(
            x + r0 * DIN, xcH, xcL, rows * DIN);
        // h1 = relu(x @ W1 + b1)
        k_gemm8<0><<<dim3(DH / 128, rows / 128), 256, 0, stream>>>(
            xcH, xcL, W1tH, W1tL, b1, h1H, h1L, nullptr,
            nullptr, nullptr, nullptr, (int)rows, DH, DIN, DIN / 32);
        // h2 = h1 @ W2 + b2
        k_gemm8<1><<<dim3(DH / 128, rows / 128), 256, 0, stream>>>(
            h1H, h1L, W2tH, W2tL, b2, h2H, h2L, nullptr,
            nullptr, nullptr, nullptr, (int)rows, DH, DH, DH / 32);
        // z partials = h2 @ W3  (split-K=8, pipelined kernel; N=256)
        k_gemm8<2><<<dim3(DZ / 128, rows / 128, KSPLIT), 256, 0, stream>>>(
            h2H, h2L, W3tH, W3tL, nullptr, nullptr, nullptr, zP,
            nullptr, nullptr, nullptr, (int)rows, DZ, DH, DH / 32 / KSPLIT);
        // finalize: sum partials + b3 -> zH/zL (residual) + z2 row norms
        k_zfin<<<(unsigned)rows, 64, 0, stream>>>(
            zP, b3, zH + r0 * DZ, zL + r0 * DZ, z2 + r0, (int)rows);
    }

    // ---- codebook norms + distance/argmin + outputs ----
    k_row_sq_norms<<<KCB / 4, 256, 0, stream>>>(cb, c2, DZ, KCB);

    // distance + argmin  [3-stream, K=256 -> 8 tiles]
    k_gemm8<3><<<dim3(KCB / 128, NROWS / 128), 256, 0, stream>>>(
        zH, zL, cbH, cbL, nullptr, nullptr, nullptr, nullptr,
        z2, c2, best, NROWS, KCB, DZ, DZ / 32);

    k_loss<<<1, 256, 0, stream>>>(best, out);
    k_output<<<NROWS, 64, 0, stream>>>(cb, best, out);
}